// Round 16
// baseline (4561.873 us; speedup 1.0000x reference)
//
#include <hip/hip_runtime.h>
#include <math.h>

#define T_    1024
#define B_    128
#define H_    512
#define I_    256
#define NTH   512
#define NC    16      // cols per wg
#define NCG   32      // wgs per rowset (= CUs per XCD)
#define RR    16      // rows per rowset (8 rowsets x 16 = 128)
#define NWG   256
#define CAP   1000000

typedef __attribute__((ext_vector_type(8))) short short8;
typedef __attribute__((ext_vector_type(4))) float f32x4;

// ---- LDS layout (bytes) ----
#define OF_WZH 16384              // 16 KB A-frags W_zh   (ast = 0..16384)
#define OF_WRH 32768              // 16 KB W_rh
#define OF_WHH 49152              // 16 KB W_hh
#define OF_WZX 65536              // 8 KB  W_zx
#define OF_WRX 73728              // 8 KB  W_rx
#define OF_WHX 81920              // 8 KB  W_hx
#define OF_CB  90112              // [16][17] f32 ctx base
#define SMEM_SZ 91232             // ~89 KB > 80 KB -> exactly 1 wg/CU

__device__ __forceinline__ unsigned short f2bf(float f) {   // RNE
    unsigned u = __float_as_uint(f);
    return (unsigned short)((u + 0x7FFFu + ((u >> 16) & 1u)) >> 16);
}
__device__ __forceinline__ float bf2f(unsigned short s) {
    return __uint_as_float(((unsigned)s) << 16);
}
__device__ __forceinline__ unsigned long long pack4(const float v[4]) {
    return (unsigned long long)f2bf(v[0]) | ((unsigned long long)f2bf(v[1]) << 16)
         | ((unsigned long long)f2bf(v[2]) << 32) | ((unsigned long long)f2bf(v[3]) << 48);
}
__device__ __forceinline__ void unpack4(unsigned long long u, float v[4]) {
    v[0] = bf2f((unsigned short)u);         v[1] = bf2f((unsigned short)(u >> 16));
    v[2] = bf2f((unsigned short)(u >> 32)); v[3] = bf2f((unsigned short)(u >> 48));
}
__device__ __forceinline__ float sigmoidf_(float x) { return 1.0f / (1.0f + expf(-x)); }

// XCD-local wait: L1-only invalidate (L1 is write-through -> never dirty ->
// nothing lost) then plain load hits the local L2 where same-XCD producers'
// write-through stores land. Capped: on breakdown we fail FAST, not hang.
// NOTE: the buffer_inv here also serves the subsequent stage_panel -- the
// CU-wide L1 invalidate happens BEFORE the flag is observed, and nothing
// re-reads stale panel lines between it and the stage (1 wg/CU).
__device__ __forceinline__ void wait_local(volatile const int* f, int tgt, bool& dead) {
    if (dead) return;
    int it = 0;
    while (1) {
        asm volatile("buffer_inv sc0" ::: "memory");
        int v = *f;
        if (v >= tgt) break;
        if (++it > CAP) { dead = true; break; }
    }
}

// stage 16x512 bf16 panel (16 KB) from local L2 -> XOR-swizzled LDS
// (no leading buffer_inv -- wait_local's inv already covers this CU)
__device__ __forceinline__ void stage_panel(char* ast, const unsigned short* src, int tid) {
    const char* s = (const char*)src;
    const int u0 = tid * 32;
    uint4 a = *(const uint4*)(s + u0);
    uint4 b = *(const uint4*)(s + u0 + 16);
    const int row = u0 >> 10;                 // 1024 B per row
    const int sw  = (row & 7) << 4;
    *(uint4*)(ast + (u0 ^ sw))        = a;
    *(uint4*)(ast + ((u0 + 16) ^ sw)) = b;
}

// stage 16x256 fp32 x rows -> bf16 swizzled LDS (rows of 512 B); cached loads
__device__ __forceinline__ void stage_x(char* ast, const float* xp, int tid) {
    const int row = tid >> 5, seg = tid & 31;
    const float* p = xp + (size_t)row * I_ + seg * 8;
    float4 f0 = *(const float4*)p, f1 = *(const float4*)(p + 4);
    float v0[4] = {f0.x, f0.y, f0.z, f0.w};
    float v1[4] = {f1.x, f1.y, f1.z, f1.w};
    const int ub = row * 512 + seg * 16;
    const int sw = (row & 7) << 4;
    *(unsigned long long*)(ast + (ub ^ sw))       = pack4(v0);
    *(unsigned long long*)(ast + ((ub + 8) ^ sw)) = pack4(v1);
}

// 16-step MFMA chain (K=512), two independent accumulators (even/odd kt)
__device__ __forceinline__ f32x4 chain16(const char* wf, const char* ast,
                                         int lane, int n, int kg, f32x4 acc) {
    const int sw = (n & 7) << 4;
    f32x4 acc1 = {0.f, 0.f, 0.f, 0.f};
    #pragma unroll
    for (int kt = 0; kt < 16; kt += 2) {
        short8 a0 = *(const short8*)(wf + kt * 1024 + lane * 16);
        short8 b0 = *(const short8*)(ast + ((n * 1024 + ((kt * 32 + kg * 8) << 1)) ^ sw));
        acc = __builtin_amdgcn_mfma_f32_16x16x32_bf16(a0, b0, acc, 0, 0, 0);
        short8 a1 = *(const short8*)(wf + (kt + 1) * 1024 + lane * 16);
        short8 b1 = *(const short8*)(ast + ((n * 1024 + (((kt + 1) * 32 + kg * 8) << 1)) ^ sw));
        acc1 = __builtin_amdgcn_mfma_f32_16x16x32_bf16(a1, b1, acc1, 0, 0, 0);
    }
    #pragma unroll
    for (int q = 0; q < 4; ++q) acc[q] += acc1[q];
    return acc;
}
// 8-step chain (K=256), same two-accumulator split
__device__ __forceinline__ f32x4 chain8(const char* wf, const char* xr,
                                        int lane, int n, int kg, f32x4 acc) {
    const int sw = (n & 7) << 4;
    f32x4 acc1 = {0.f, 0.f, 0.f, 0.f};
    #pragma unroll
    for (int kt = 0; kt < 8; kt += 2) {
        short8 a0 = *(const short8*)(wf + kt * 1024 + lane * 16);
        short8 b0 = *(const short8*)(xr + ((n * 512 + ((kt * 32 + kg * 8) << 1)) ^ sw));
        acc = __builtin_amdgcn_mfma_f32_16x16x32_bf16(a0, b0, acc, 0, 0, 0);
        short8 a1 = *(const short8*)(wf + (kt + 1) * 1024 + lane * 16);
        short8 b1 = *(const short8*)(xr + ((n * 512 + (((kt + 1) * 32 + kg * 8) << 1)) ^ sw));
        acc1 = __builtin_amdgcn_mfma_f32_16x16x32_bf16(a1, b1, acc1, 0, 0, 0);
    }
    #pragma unroll
    for (int q = 0; q < 4; ++q) acc[q] += acc1[q];
    return acc;
}

__global__ __launch_bounds__(NTH, 1) void scagru_x8(
    const float* __restrict__ input, const float* __restrict__ state,
    const float* __restrict__ W_zh, const float* __restrict__ W_zx, const float* __restrict__ b_z,
    const float* __restrict__ W_rh, const float* __restrict__ W_rx, const float* __restrict__ b_r,
    const float* __restrict__ W_hh, const float* __restrict__ W_hx, const float* __restrict__ b_h,
    const float* __restrict__ W_ch, const float* __restrict__ b_c,
    float* __restrict__ out,
    unsigned short* __restrict__ hP, unsigned short* __restrict__ hrP,
    int* __restrict__ claim, int* __restrict__ ready,
    int* __restrict__ hfl, int* __restrict__ hrfl)
{
    const int tid  = threadIdx.x;
    const int lane = tid & 63;
    const int wv   = tid >> 6;                 // 0..7
    const int n    = lane & 15;                // batch row within tile (C col)
    const int kg   = lane >> 4;
    const int m0   = kg * 4;                   // hidden-col quad (C rows)

    __shared__ __align__(16) char smem[SMEM_SZ];
    __shared__ int role_s;
    char*  ast   = smem;
    float* cbase = (float*)(smem + OF_CB);

    // ---- claim XCD-local role; zero own flags; arrive at MALL rendezvous ----
    if (tid == 0) {
        unsigned xcd;
        asm volatile("s_getreg_b32 %0, hwreg(20, 0, 4)" : "=s"(xcd));   // HW_REG_XCC_ID
        xcd &= 7;
        int rank = __hip_atomic_fetch_add(&claim[xcd], 1, __ATOMIC_RELAXED, __HIP_MEMORY_SCOPE_AGENT);
        int role = (rank < NCG) ? (int)xcd * NCG + rank : -1;
        role_s = role;
        if (role >= 0) {
            hfl[role] = 0; hrfl[role] = 0;                        // plain -> local L2
            asm volatile("s_waitcnt vmcnt(0)" ::: "memory");
        }
        __hip_atomic_fetch_add(ready, 1, __ATOMIC_RELAXED, __HIP_MEMORY_SCOPE_AGENT);
    }
    __syncthreads();
    const int role = role_s;
    if (role < 0) return;
    const int rs = role >> 5, cg = role & 31;
    const int c0 = cg * NC, r0 = rs * RR;

    unsigned short* hPrs  = hP  + (size_t)rs * RR * H_;
    unsigned short* hrPrs = hrP + (size_t)rs * RR * H_;
    volatile int* hfl_rs  = (volatile int*)(hfl  + rs * NCG);
    volatile int* hrfl_rs = (volatile int*)(hrfl + rs * NCG);

    // ---- one-time: 6 weight slices -> MFMA A-frags (72 wave-tasks) ----
    for (int task = wv; task < 72; task += 8) {
        const float* W; char* dst; int kt;
        if      (task < 16) { W = W_zh; dst = smem + OF_WZH; kt = task; }
        else if (task < 32) { W = W_rh; dst = smem + OF_WRH; kt = task - 16; }
        else if (task < 48) { W = W_hh; dst = smem + OF_WHH; kt = task - 32; }
        else if (task < 56) { W = W_zx; dst = smem + OF_WZX; kt = task - 48; }
        else if (task < 64) { W = W_rx; dst = smem + OF_WRX; kt = task - 56; }
        else                { W = W_hx; dst = smem + OF_WHX; kt = task - 64; }
        short8 a;
        #pragma unroll
        for (int j = 0; j < 8; ++j)
            a[j] = (short)f2bf(W[(size_t)(kt * 32 + kg * 8 + j) * H_ + c0 + n]);
        *(short8*)(dst + kt * 1024 + lane * 16) = a;
    }

    // ---- one-time: context base relu(state@W_ch + b_c) for our 16x16 block ----
    if (tid < 256) {
        const int r = tid >> 4, cl = tid & 15;
        const float* srow = state + (size_t)(r0 + r) * H_;
        float acc = 0.f;
        #pragma unroll 8
        for (int k = 0; k < H_; ++k)
            acc = fmaf(srow[k], W_ch[(size_t)k * H_ + cl + c0], acc);
        cbase[r * 17 + cl] = fmaxf(acc + b_c[c0 + cl], 0.f);
    }

    // ---- stage x(t=0) ----
    stage_x(ast, input + (size_t)r0 * I_, tid);
    __syncthreads();

    // ---- per-wave persistent registers ----
    f32x4 cz = {0,0,0,0}, cr = {0,0,0,0}, ch = {0,0,0,0};
    f32x4 xz = {0,0,0,0}, xr = {0,0,0,0}, xh = {0,0,0,0};
    f32x4 hp = {0,0,0,0}, zfrag = {0,0,0,0};
    if (wv == 0) {
        #pragma unroll
        for (int q = 0; q < 4; ++q) {
            float b = cbase[n * 17 + m0 + q];
            cz[q] = b + b_z[c0 + m0 + q];
            ch[q] = b + b_h[c0 + m0 + q];
        }
        xz = chain8(smem + OF_WZX, ast, lane, n, kg, cz);
        xh = chain8(smem + OF_WHX, ast, lane, n, kg, ch);
        hp = *(const f32x4*)(state + (size_t)(r0 + n) * H_ + c0 + m0);
    } else if (wv == 1) {
        #pragma unroll
        for (int q = 0; q < 4; ++q)
            cr[q] = cbase[n * 17 + m0 + q] + b_r[c0 + m0 + q];
        xr = chain8(smem + OF_WRX, ast, lane, n, kg, cr);
    }

    // ---- rendezvous: all 256 wgs claimed + zeroed (capped MALL poll) ----
    if (tid == 0) {
        int it = 0;
        while (__hip_atomic_load(ready, __ATOMIC_RELAXED, __HIP_MEMORY_SCOPE_AGENT) < NWG) {
            if (++it > 4000000) break;
            __builtin_amdgcn_s_sleep(8);
        }
    }
    __syncthreads();

    // ---- publish h_0 (plain stores -> local L2) ----
    if (wv == 0) {
        float v[4] = {hp[0], hp[1], hp[2], hp[3]};
        *(unsigned long long*)(hPrs + (size_t)n * H_ + c0 + m0) = pack4(v);
    }
    __syncthreads();
    if (tid == 0) *(volatile int*)&hfl[role] = 1;

    bool dead = false;

    for (int t = 0; t < T_; ++t) {
        // ================= phase A: z & r =================
        if (tid < NCG) wait_local(&hfl_rs[tid], t + 1, dead);
        __syncthreads();
        stage_panel(ast, hPrs, tid);
        __syncthreads();

        if (wv == 0) {
            f32x4 acc = chain16(smem + OF_WZH, ast, lane, n, kg, xz);
            #pragma unroll
            for (int q = 0; q < 4; ++q) zfrag[q] = sigmoidf_(acc[q]);
        } else if (wv == 1) {
            f32x4 acc = chain16(smem + OF_WRH, ast, lane, n, kg, xr);
            const int sw = (n & 7) << 4;
            float hv[4], v[4];
            unpack4(*(const unsigned long long*)(ast + ((n * 1024 + ((c0 + m0) << 1)) ^ sw)), hv);
            #pragma unroll
            for (int q = 0; q < 4; ++q) v[q] = sigmoidf_(acc[q]) * hv[q];
            *(unsigned long long*)(hrPrs + (size_t)n * H_ + c0 + m0) = pack4(v);
        } else if (wv == 4 && t + 1 < T_) {
            // R16: L2-warm input(t+1) -- one dword per 64-B line, 4 lines/lane,
            // results kept alive (no DCE) but never consumed: zero race surface.
            const char* p = (const char*)(input + ((size_t)(t + 1) * B_ + r0) * I_);
            #pragma unroll
            for (int j = 0; j < 4; ++j) {
                unsigned v = *(const unsigned*)(p + lane * 64 + j * 4096);
                asm volatile("" :: "v"(v));
            }
        }
        __syncthreads();                                    // drains hr stores
        if (tid == 0) *(volatile int*)&hrfl_rs[cg] = t + 1;

        // ================= phase B: h-candidate + update =================
        if (tid < NCG) wait_local(&hrfl_rs[tid], t + 1, dead);
        __syncthreads();
        stage_panel(ast, hrPrs, tid);
        __syncthreads();

        if (wv == 0) {
            f32x4 acc = chain16(smem + OF_WHH, ast, lane, n, kg, xh);
            float hn[4];
            #pragma unroll
            for (int q = 0; q < 4; ++q) {
                float hc = tanhf(acc[q]);
                hn[q] = (1.f - zfrag[q]) * hp[q] + zfrag[q] * hc;
                hp[q] = hn[q];
            }
            *(unsigned long long*)(hPrs + (size_t)n * H_ + c0 + m0) = pack4(hn);
            if (t == T_ - 1)
                *(float4*)(out + (size_t)(r0 + n) * H_ + c0 + m0) =
                    make_float4(hn[0], hn[1], hn[2], hn[3]);
        }
        __syncthreads();                                    // drains h stores
        if (tid == 0) *(volatile int*)&hfl_rs[cg] = t + 2;

        // ---- x-projection for t+1 (local; L2-warm after R16 prefetch) ----
        if (t + 1 < T_) {
            stage_x(ast, input + ((size_t)(t + 1) * B_ + r0) * I_, tid);
            __syncthreads();
            if (wv == 0) {
                xz = chain8(smem + OF_WZX, ast, lane, n, kg, cz);
                xh = chain8(smem + OF_WHX, ast, lane, n, kg, ch);
            } else if (wv == 1) {
                xr = chain8(smem + OF_WRX, ast, lane, n, kg, cr);
            }
            // next loop's post-poll __syncthreads orders these reads vs restage
        }
    }
}

extern "C" void kernel_launch(void* const* d_in, const int* in_sizes, int n_in,
                              void* d_out, int out_size, void* d_ws, size_t ws_size,
                              hipStream_t stream)
{
    const float* input = (const float*)d_in[0];
    const float* state = (const float*)d_in[1];
    const float* W_zh  = (const float*)d_in[2];
    const float* W_zx  = (const float*)d_in[3];
    const float* b_z   = (const float*)d_in[4];
    const float* W_rh  = (const float*)d_in[5];
    const float* W_rx  = (const float*)d_in[6];
    const float* b_r   = (const float*)d_in[7];
    const float* W_hh  = (const float*)d_in[8];
    const float* W_hx  = (const float*)d_in[9];
    const float* b_h   = (const float*)d_in[10];
    const float* W_ch  = (const float*)d_in[11];
    const float* b_c   = (const float*)d_in[12];

    float* out = (float*)d_out;
    char*  ws  = (char*)d_ws;

    unsigned short* hP  = (unsigned short*)(ws);              // [8][16][512] bf16 = 128 KB
    unsigned short* hrP = (unsigned short*)(ws + 131072);     // [8][16][512] bf16 = 128 KB
    char* ctrl = ws + 262144;
    int* claim = (int*)(ctrl);                                // [8]
    int* ready = (int*)(ctrl + 128);                          // [1]
    int* hfl   = (int*)(ctrl + 512);                          // [8][32]
    int* hrfl  = (int*)(ctrl + 1536);                         // [8][32]

    hipMemsetAsync(ctrl, 0, 256, stream);                     // claim + ready only

    scagru_x8<<<dim3(NWG), dim3(NTH), 0, stream>>>(
        input, state,
        W_zh, W_zx, b_z, W_rh, W_rx, b_r, W_hh, W_hx, b_h, W_ch, b_c,
        out, hP, hrP, claim, ready, hfl, hrfl);
}

// Round 17
// 4233.929 us; speedup vs baseline: 1.0775x; 1.0775x over previous
//
#include <hip/hip_runtime.h>
#include <math.h>

#define T_    1024
#define B_    128
#define H_    512
#define I_    256
#define NTH   512
#define NC    16      // cols per wg
#define NCG   32      // wgs per rowset (= CUs per XCD)
#define RR    16      // rows per rowset (8 rowsets x 16 = 128)
#define NWG   256
#define CAP   1000000

typedef __attribute__((ext_vector_type(8))) short short8;
typedef __attribute__((ext_vector_type(4))) float f32x4;

// ---- LDS layout (bytes) ----
#define OF_WZH 16384              // 16 KB A-frags W_zh   (ast = 0..16384)
#define OF_WRH 32768              // 16 KB W_rh
#define OF_WHH 49152              // 16 KB W_hh
#define OF_WZX 65536              // 8 KB  W_zx
#define OF_WRX 73728              // 8 KB  W_rx
#define OF_WHX 81920              // 8 KB  W_hx
#define OF_CB  90112              // [16][17] f32 ctx base
#define SMEM_SZ 91232             // ~89 KB > 80 KB -> exactly 1 wg/CU

__device__ __forceinline__ unsigned short f2bf(float f) {   // RNE
    unsigned u = __float_as_uint(f);
    return (unsigned short)((u + 0x7FFFu + ((u >> 16) & 1u)) >> 16);
}
__device__ __forceinline__ float bf2f(unsigned short s) {
    return __uint_as_float(((unsigned)s) << 16);
}
__device__ __forceinline__ unsigned long long pack4(const float v[4]) {
    return (unsigned long long)f2bf(v[0]) | ((unsigned long long)f2bf(v[1]) << 16)
         | ((unsigned long long)f2bf(v[2]) << 32) | ((unsigned long long)f2bf(v[3]) << 48);
}
__device__ __forceinline__ void unpack4(unsigned long long u, float v[4]) {
    v[0] = bf2f((unsigned short)u);         v[1] = bf2f((unsigned short)(u >> 16));
    v[2] = bf2f((unsigned short)(u >> 32)); v[3] = bf2f((unsigned short)(u >> 48));
}
__device__ __forceinline__ float sigmoidf_(float x) { return 1.0f / (1.0f + expf(-x)); }

// XCD-local wait: L1-only invalidate (L1 is write-through -> never dirty ->
// nothing lost) then plain load hits the local L2 where same-XCD producers'
// write-through stores land. Capped: on breakdown we fail FAST, not hang.
// NOTE: the buffer_inv here also serves the subsequent stage_panel -- the
// CU-wide L1 invalidate happens BEFORE the flag is observed, and nothing
// re-reads stale panel lines between it and the stage (1 wg/CU).
__device__ __forceinline__ void wait_local(volatile const int* f, int tgt, bool& dead) {
    if (dead) return;
    int it = 0;
    while (1) {
        asm volatile("buffer_inv sc0" ::: "memory");
        int v = *f;
        if (v >= tgt) break;
        if (++it > CAP) { dead = true; break; }
    }
}

// stage 16x512 bf16 panel (16 KB) from local L2 -> XOR-swizzled LDS
// (no leading buffer_inv -- wait_local's inv already covers this CU;
//  every call site is immediately preceded by a wait_local + __syncthreads)
__device__ __forceinline__ void stage_panel(char* ast, const unsigned short* src, int tid) {
    const char* s = (const char*)src;
    const int u0 = tid * 32;
    uint4 a = *(const uint4*)(s + u0);
    uint4 b = *(const uint4*)(s + u0 + 16);
    const int row = u0 >> 10;                 // 1024 B per row
    const int sw  = (row & 7) << 4;
    *(uint4*)(ast + (u0 ^ sw))        = a;
    *(uint4*)(ast + ((u0 + 16) ^ sw)) = b;
}

// stage 16x256 fp32 x rows -> bf16 swizzled LDS (rows of 512 B); cached loads
__device__ __forceinline__ void stage_x(char* ast, const float* xp, int tid) {
    const int row = tid >> 5, seg = tid & 31;
    const float* p = xp + (size_t)row * I_ + seg * 8;
    float4 f0 = *(const float4*)p, f1 = *(const float4*)(p + 4);
    float v0[4] = {f0.x, f0.y, f0.z, f0.w};
    float v1[4] = {f1.x, f1.y, f1.z, f1.w};
    const int ub = row * 512 + seg * 16;
    const int sw = (row & 7) << 4;
    *(unsigned long long*)(ast + (ub ^ sw))       = pack4(v0);
    *(unsigned long long*)(ast + ((ub + 8) ^ sw)) = pack4(v1);
}

// 16-step MFMA chain (K=512), split into two independent accumulators
// (even/odd kt) to halve the serial MFMA dependency chain; summed at end.
__device__ __forceinline__ f32x4 chain16(const char* wf, const char* ast,
                                         int lane, int n, int kg, f32x4 acc) {
    const int sw = (n & 7) << 4;
    f32x4 acc1 = {0.f, 0.f, 0.f, 0.f};
    #pragma unroll
    for (int kt = 0; kt < 16; kt += 2) {
        short8 a0 = *(const short8*)(wf + kt * 1024 + lane * 16);
        short8 b0 = *(const short8*)(ast + ((n * 1024 + ((kt * 32 + kg * 8) << 1)) ^ sw));
        acc = __builtin_amdgcn_mfma_f32_16x16x32_bf16(a0, b0, acc, 0, 0, 0);
        short8 a1 = *(const short8*)(wf + (kt + 1) * 1024 + lane * 16);
        short8 b1 = *(const short8*)(ast + ((n * 1024 + (((kt + 1) * 32 + kg * 8) << 1)) ^ sw));
        acc1 = __builtin_amdgcn_mfma_f32_16x16x32_bf16(a1, b1, acc1, 0, 0, 0);
    }
    #pragma unroll
    for (int q = 0; q < 4; ++q) acc[q] += acc1[q];
    return acc;
}
// 8-step chain (K=256), same two-accumulator split
__device__ __forceinline__ f32x4 chain8(const char* wf, const char* xr,
                                        int lane, int n, int kg, f32x4 acc) {
    const int sw = (n & 7) << 4;
    f32x4 acc1 = {0.f, 0.f, 0.f, 0.f};
    #pragma unroll
    for (int kt = 0; kt < 8; kt += 2) {
        short8 a0 = *(const short8*)(wf + kt * 1024 + lane * 16);
        short8 b0 = *(const short8*)(xr + ((n * 512 + ((kt * 32 + kg * 8) << 1)) ^ sw));
        acc = __builtin_amdgcn_mfma_f32_16x16x32_bf16(a0, b0, acc, 0, 0, 0);
        short8 a1 = *(const short8*)(wf + (kt + 1) * 1024 + lane * 16);
        short8 b1 = *(const short8*)(xr + ((n * 512 + (((kt + 1) * 32 + kg * 8) << 1)) ^ sw));
        acc1 = __builtin_amdgcn_mfma_f32_16x16x32_bf16(a1, b1, acc1, 0, 0, 0);
    }
    #pragma unroll
    for (int q = 0; q < 4; ++q) acc[q] += acc1[q];
    return acc;
}

__global__ __launch_bounds__(NTH, 1) void scagru_x8(
    const float* __restrict__ input, const float* __restrict__ state,
    const float* __restrict__ W_zh, const float* __restrict__ W_zx, const float* __restrict__ b_z,
    const float* __restrict__ W_rh, const float* __restrict__ W_rx, const float* __restrict__ b_r,
    const float* __restrict__ W_hh, const float* __restrict__ W_hx, const float* __restrict__ b_h,
    const float* __restrict__ W_ch, const float* __restrict__ b_c,
    float* __restrict__ out,
    unsigned short* __restrict__ hP, unsigned short* __restrict__ hrP,
    int* __restrict__ claim, int* __restrict__ ready,
    int* __restrict__ hfl, int* __restrict__ hrfl)
{
    const int tid  = threadIdx.x;
    const int lane = tid & 63;
    const int wv   = tid >> 6;                 // 0..7
    const int n    = lane & 15;                // batch row within tile (C col)
    const int kg   = lane >> 4;
    const int m0   = kg * 4;                   // hidden-col quad (C rows)

    __shared__ __align__(16) char smem[SMEM_SZ];
    __shared__ int role_s;
    char*  ast   = smem;
    float* cbase = (float*)(smem + OF_CB);

    // ---- claim XCD-local role; zero own flags; arrive at MALL rendezvous ----
    if (tid == 0) {
        unsigned xcd;
        asm volatile("s_getreg_b32 %0, hwreg(20, 0, 4)" : "=s"(xcd));   // HW_REG_XCC_ID
        xcd &= 7;
        int rank = __hip_atomic_fetch_add(&claim[xcd], 1, __ATOMIC_RELAXED, __HIP_MEMORY_SCOPE_AGENT);
        int role = (rank < NCG) ? (int)xcd * NCG + rank : -1;
        role_s = role;
        if (role >= 0) {
            hfl[role] = 0; hrfl[role] = 0;                        // plain -> local L2
            asm volatile("s_waitcnt vmcnt(0)" ::: "memory");
        }
        __hip_atomic_fetch_add(ready, 1, __ATOMIC_RELAXED, __HIP_MEMORY_SCOPE_AGENT);
    }
    __syncthreads();
    const int role = role_s;
    if (role < 0) return;
    const int rs = role >> 5, cg = role & 31;
    const int c0 = cg * NC, r0 = rs * RR;

    unsigned short* hPrs  = hP  + (size_t)rs * RR * H_;
    unsigned short* hrPrs = hrP + (size_t)rs * RR * H_;
    volatile int* hfl_rs  = (volatile int*)(hfl  + rs * NCG);
    volatile int* hrfl_rs = (volatile int*)(hrfl + rs * NCG);

    // ---- one-time: 6 weight slices -> MFMA A-frags (72 wave-tasks) ----
    for (int task = wv; task < 72; task += 8) {
        const float* W; char* dst; int kt;
        if      (task < 16) { W = W_zh; dst = smem + OF_WZH; kt = task; }
        else if (task < 32) { W = W_rh; dst = smem + OF_WRH; kt = task - 16; }
        else if (task < 48) { W = W_hh; dst = smem + OF_WHH; kt = task - 32; }
        else if (task < 56) { W = W_zx; dst = smem + OF_WZX; kt = task - 48; }
        else if (task < 64) { W = W_rx; dst = smem + OF_WRX; kt = task - 56; }
        else                { W = W_hx; dst = smem + OF_WHX; kt = task - 64; }
        short8 a;
        #pragma unroll
        for (int j = 0; j < 8; ++j)
            a[j] = (short)f2bf(W[(size_t)(kt * 32 + kg * 8 + j) * H_ + c0 + n]);
        *(short8*)(dst + kt * 1024 + lane * 16) = a;
    }

    // ---- one-time: context base relu(state@W_ch + b_c) for our 16x16 block ----
    if (tid < 256) {
        const int r = tid >> 4, cl = tid & 15;
        const float* srow = state + (size_t)(r0 + r) * H_;
        float acc = 0.f;
        #pragma unroll 8
        for (int k = 0; k < H_; ++k)
            acc = fmaf(srow[k], W_ch[(size_t)k * H_ + cl + c0], acc);
        cbase[r * 17 + cl] = fmaxf(acc + b_c[c0 + cl], 0.f);
    }

    // ---- stage x(t=0) ----
    stage_x(ast, input + (size_t)r0 * I_, tid);
    __syncthreads();

    // ---- per-wave persistent registers ----
    f32x4 cz = {0,0,0,0}, cr = {0,0,0,0}, ch = {0,0,0,0};
    f32x4 xz = {0,0,0,0}, xr = {0,0,0,0}, xh = {0,0,0,0};
    f32x4 hp = {0,0,0,0}, zfrag = {0,0,0,0};
    if (wv == 0) {
        #pragma unroll
        for (int q = 0; q < 4; ++q) {
            float b = cbase[n * 17 + m0 + q];
            cz[q] = b + b_z[c0 + m0 + q];
            ch[q] = b + b_h[c0 + m0 + q];
        }
        xz = chain8(smem + OF_WZX, ast, lane, n, kg, cz);
        xh = chain8(smem + OF_WHX, ast, lane, n, kg, ch);
        hp = *(const f32x4*)(state + (size_t)(r0 + n) * H_ + c0 + m0);
    } else if (wv == 1) {
        #pragma unroll
        for (int q = 0; q < 4; ++q)
            cr[q] = cbase[n * 17 + m0 + q] + b_r[c0 + m0 + q];
        xr = chain8(smem + OF_WRX, ast, lane, n, kg, cr);
    }

    // ---- rendezvous: all 256 wgs claimed + zeroed (capped MALL poll) ----
    if (tid == 0) {
        int it = 0;
        while (__hip_atomic_load(ready, __ATOMIC_RELAXED, __HIP_MEMORY_SCOPE_AGENT) < NWG) {
            if (++it > 4000000) break;
            __builtin_amdgcn_s_sleep(8);
        }
    }
    __syncthreads();

    // ---- publish h_0 (plain stores -> local L2) ----
    if (wv == 0) {
        float v[4] = {hp[0], hp[1], hp[2], hp[3]};
        *(unsigned long long*)(hPrs + (size_t)n * H_ + c0 + m0) = pack4(v);
    }
    __syncthreads();
    if (tid == 0) *(volatile int*)&hfl[role] = 1;

    bool dead = false;

    for (int t = 0; t < T_; ++t) {
        // ================= phase A: z & r =================
        if (tid < NCG) wait_local(&hfl_rs[tid], t + 1, dead);
        __syncthreads();
        stage_panel(ast, hPrs, tid);
        __syncthreads();

        if (wv == 0) {
            f32x4 acc = chain16(smem + OF_WZH, ast, lane, n, kg, xz);
            #pragma unroll
            for (int q = 0; q < 4; ++q) zfrag[q] = sigmoidf_(acc[q]);
        } else if (wv == 1) {
            f32x4 acc = chain16(smem + OF_WRH, ast, lane, n, kg, xr);
            const int sw = (n & 7) << 4;
            float hv[4], v[4];
            unpack4(*(const unsigned long long*)(ast + ((n * 1024 + ((c0 + m0) << 1)) ^ sw)), hv);
            #pragma unroll
            for (int q = 0; q < 4; ++q) v[q] = sigmoidf_(acc[q]) * hv[q];
            *(unsigned long long*)(hrPrs + (size_t)n * H_ + c0 + m0) = pack4(v);
        }
        __syncthreads();                                    // drains hr stores
        if (tid == 0) *(volatile int*)&hrfl_rs[cg] = t + 1;

        // ================= phase B: h-candidate + update =================
        if (tid < NCG) wait_local(&hrfl_rs[tid], t + 1, dead);
        __syncthreads();
        stage_panel(ast, hrPrs, tid);
        __syncthreads();

        if (wv == 0) {
            f32x4 acc = chain16(smem + OF_WHH, ast, lane, n, kg, xh);
            float hn[4];
            #pragma unroll
            for (int q = 0; q < 4; ++q) {
                float hc = tanhf(acc[q]);
                hn[q] = (1.f - zfrag[q]) * hp[q] + zfrag[q] * hc;
                hp[q] = hn[q];
            }
            *(unsigned long long*)(hPrs + (size_t)n * H_ + c0 + m0) = pack4(hn);
            if (t == T_ - 1)
                *(float4*)(out + (size_t)(r0 + n) * H_ + c0 + m0) =
                    make_float4(hn[0], hn[1], hn[2], hn[3]);
        }
        __syncthreads();                                    // drains h stores
        if (tid == 0) *(volatile int*)&hfl_rs[cg] = t + 2;

        // ---- x-projection for t+1 (local; hidden behind others' phases) ----
        if (t + 1 < T_) {
            stage_x(ast, input + ((size_t)(t + 1) * B_ + r0) * I_, tid);
            __syncthreads();
            if (wv == 0) {
                xz = chain8(smem + OF_WZX, ast, lane, n, kg, cz);
                xh = chain8(smem + OF_WHX, ast, lane, n, kg, ch);
            } else if (wv == 1) {
                xr = chain8(smem + OF_WRX, ast, lane, n, kg, cr);
            }
            // next loop's post-poll __syncthreads orders these reads vs restage
        }
    }
}

extern "C" void kernel_launch(void* const* d_in, const int* in_sizes, int n_in,
                              void* d_out, int out_size, void* d_ws, size_t ws_size,
                              hipStream_t stream)
{
    const float* input = (const float*)d_in[0];
    const float* state = (const float*)d_in[1];
    const float* W_zh  = (const float*)d_in[2];
    const float* W_zx  = (const float*)d_in[3];
    const float* b_z   = (const float*)d_in[4];
    const float* W_rh  = (const float*)d_in[5];
    const float* W_rx  = (const float*)d_in[6];
    const float* b_r   = (const float*)d_in[7];
    const float* W_hh  = (const float*)d_in[8];
    const float* W_hx  = (const float*)d_in[9];
    const float* b_h   = (const float*)d_in[10];
    const float* W_ch  = (const float*)d_in[11];
    const float* b_c   = (const float*)d_in[12];

    float* out = (float*)d_out;
    char*  ws  = (char*)d_ws;

    unsigned short* hP  = (unsigned short*)(ws);              // [8][16][512] bf16 = 128 KB
    unsigned short* hrP = (unsigned short*)(ws + 131072);     // [8][16][512] bf16 = 128 KB
    char* ctrl = ws + 262144;
    int* claim = (int*)(ctrl);                                // [8]
    int* ready = (int*)(ctrl + 128);                          // [1]
    int* hfl   = (int*)(ctrl + 512);                          // [8][32]
    int* hrfl  = (int*)(ctrl + 1536);                         // [8][32]

    hipMemsetAsync(ctrl, 0, 256, stream);                     // claim + ready only

    scagru_x8<<<dim3(NWG), dim3(NTH), 0, stream>>>(
        input, state,
        W_zh, W_zx, b_z, W_rh, W_rx, b_r, W_hh, W_hx, b_h, W_ch, b_c,
        out, hP, hrP, claim, ready, hfl, hrfl);
}